// Round 2
// baseline (139.725 us; speedup 1.0000x reference)
//
#include <hip/hip_runtime.h>

// Problem shape (fixed; established r6/r7/r10/r11 of prior session):
//   d_in[0]: (1024, 256) int32  ids in [0, 30522)
//   d_in[1]: (1024, 256) f32    weights uniform [0,1)
//   d_out:   (1024, 30522) f32  -- value = bf16(RN-even) of scatter-max of the
//            per-token weight into its vocab slot, 0 baseline, stored as f32.
//
// r1 findings: harness re-poisons the 500 MB output allocation with a
// fillBufferAligned (~76 us) inside the timed window every iteration --
// that part is an unremovable floor. Our fused kernel is the rest
// (~55 us incl. overhead) vs a ~21 us write-roofline (125 MB out, 6.3 TB/s).
//
// r2: close that gap. 4 vocab chunks per row (7632 slots, 30.5 KB LDS)
// -> 5 blocks/CU (was 2), uint4 LDS zeroing (8 ds_write_b128 iters, was 60
// ds_write_b32), nontemporal 8 B output stores (write-once data; don't
// fight the poison's dirty L3 lines). Zero baseline still comes from the
// LDS zeroing; no memset, no global atomics, each output byte written once.
#define VOCAB 30522
#define SEQ   256
#define CH    7632   // slots per chunk; chunks 0-2 = 7632, chunk 3 = 7626
#define NCH   4

// bf16 RN-even of a nonneg f32, re-expanded to f32 bits. Nonneg IEEE bit
// patterns are order-isomorphic to values and RN-even is monotone on nonneg
// inputs, so round-then-max == max-then-round (bit-exact vs reference).
__device__ __forceinline__ unsigned bf16_bits(float w) {
    const unsigned u = __float_as_uint(w);
    return ((u + 0x7FFFu + ((u >> 16) & 1u)) >> 16) << 16;
}

extern "C" __global__ __launch_bounds__(256)
void TargetEncoder_532575944857_kernel(const int* __restrict__ ids,
                                       const float* __restrict__ ws,
                                       unsigned int* __restrict__ out,
                                       int n_rows) {
    __shared__ __align__(16) unsigned int tab[CH];  // 30,528 B -> 5 blocks/CU

    const int blk  = blockIdx.x;
    const int b    = blk >> 2;            // row
    const int c    = blk & 3;             // vocab chunk
    const int t    = threadIdx.x;
    const int base = c * CH;
    const int lim  = (c == 3) ? (VOCAB - 3 * CH) : CH;   // 7626 : 7632

    if (b >= n_rows) return;

    // Phase 1: zero the LDS table with ds_write_b128 (this IS the 0 baseline).
    {
        const uint4 z = make_uint4(0u, 0u, 0u, 0u);
        uint4* t4 = (uint4*)tab;
        for (int i = t; i < CH / 4; i += 256) t4[i] = z;   // 1908 words4, 8 iters
    }
    __syncthreads();

    // Phase 2: scatter-max this row's 256 tokens into LDS. One token/thread;
    // duplicates resolved by the LDS atomic; ids outside this chunk (and any
    // defensive out-of-range id) fail the unsigned bound check.
    {
        const int      tok = b * SEQ + t;
        const int      id  = ids[tok];
        const unsigned val = bf16_bits(ws[tok]);
        const int      loc = id - base;
        if (val != 0u && (unsigned)loc < (unsigned)lim)
            atomicMax(&tab[loc], val);
    }
    __syncthreads();

    // Phase 3: stream the chunk to global, coalesced 8 B/lane nontemporal
    // stores (512 B/wave). Chunk byte offset = b*122088 + c*30528, both
    // % 8 == 0; lim is even for all chunks -> no scalar tail.
    unsigned long long*       dst = (unsigned long long*)(out + (long long)b * VOCAB + base);
    const unsigned long long* src = (const unsigned long long*)tab;
    const int n2 = lim >> 1;              // 3816 : 3813
    for (int j = t; j < n2; j += 256)
        __builtin_nontemporal_store(src[j], &dst[j]);
}

extern "C" void kernel_launch(void* const* d_in, const int* in_sizes, int n_in,
                              void* d_out, int out_size, void* d_ws, size_t ws_size,
                              hipStream_t stream) {
    const int*   ids = (const int*)d_in[0];
    const float* ws  = (const float*)d_in[1];
    const int n_tok  = in_sizes[0];        // 262144
    const int n_rows = n_tok / SEQ;        // 1024

    TargetEncoder_532575944857_kernel<<<dim3(n_rows * NCH), dim3(256), 0, stream>>>(
        ids, ws, (unsigned int*)d_out, n_rows);
}

// Round 3
// 136.604 us; speedup vs baseline: 1.0228x; 1.0228x over previous
//
#include <hip/hip_runtime.h>

// Problem shape (fixed):
//   d_in[0]: (1024, 256) int32  ids in [0, 30522)
//   d_in[1]: (1024, 256) f32    weights uniform [0,1)
//   d_out:   (1024, 30522) f32  -- value = bf16(RN-even) of scatter-max of the
//            per-token weight into its vocab slot, 0 baseline, stored as f32.
//
// r0-r2 model reconciliation: out_size is ELEMENTS (31,254,528). The 500 MB
// (488,352 KB) fillBufferAligned seen every iteration is the HARNESS's
// re-poison of the full allocation, inside the timed window (~78 us,
// unremovable). r0 = 78 + 19 (our 125 MB memset) + ~40 (atomics, L3-cold
// because r0's *500 MB* memset evicted the output region) = 136.5.
// r1/r2 fused-LDS kernel = ~54-60 us (125 MB of L3-missing stores + LDS
// zero + 2 barriers/block).
//
// r3: memset exactly 125 MB (runtime fill path, ~19 us) + trivial global
// atomicMax scatter. The 125 MB fill leaves the WHOLE output region
// dirty-resident in the 256 MB L3, so the 256K scattered RMW atomics are
// L3 hits and hide their latency across 262K threads (~10-15 us).
#define VOCAB 30522
#define SEQ   256

// bf16 RN-even of a nonneg f32, re-expanded to f32 bits. Nonneg IEEE bit
// patterns are order-isomorphic to values and RN-even is monotone on nonneg
// inputs, so round-then-max == max-then-round (bit-exact vs reference).
// Scatter-max with u32 atomicMax on the bit patterns is therefore exact;
// duplicates resolved by the atomic; baseline 0 from the memset.
extern "C" __global__ __launch_bounds__(256)
void TargetEncoder_532575944857_kernel(const int* __restrict__ ids,
                                       const float* __restrict__ ws,
                                       unsigned int* __restrict__ out,
                                       int n_tok) {
    const int t = blockIdx.x * blockDim.x + threadIdx.x;
    if (t >= n_tok) return;

    const int   id = ids[t];
    const float w  = ws[t];
    if ((unsigned)id >= (unsigned)VOCAB) return;  // defensive: never fault

    const unsigned u   = __float_as_uint(w);
    const unsigned val = ((u + 0x7FFFu + ((u >> 16) & 1u)) >> 16) << 16;  // RN-even bf16 bits
    if (val == 0u) return;  // baseline already 0

    const int b = t >> 8;  // t / SEQ; consecutive blocks -> consecutive rows
    atomicMax(out + ((long long)b * VOCAB + id), val);
}

extern "C" void kernel_launch(void* const* d_in, const int* in_sizes, int n_in,
                              void* d_out, int out_size, void* d_ws, size_t ws_size,
                              hipStream_t stream) {
    const int*   ids = (const int*)d_in[0];
    const float* ws  = (const float*)d_in[1];
    const int n_tok  = in_sizes[0];  // 262144

    // Zero exactly the compared region: out_size ELEMENTS x 4 B = 125,018,112 B.
    // Runtime fill path measured at ~6.5 TB/s => ~19 us, and it leaves the
    // region dirty-resident in L3 for the atomics that follow.
    (void)hipMemsetAsync(d_out, 0, (size_t)out_size * sizeof(float), stream);

    TargetEncoder_532575944857_kernel<<<(n_tok + 255) / 256, 256, 0, stream>>>(
        ids, ws, (unsigned int*)d_out, n_tok);
}

// Round 4
// 130.336 us; speedup vs baseline: 1.0720x; 1.0481x over previous
//
#include <hip/hip_runtime.h>

// Problem shape (fixed):
//   d_in[0]: (1024, 256) int32  ids in [0, 30522)
//   d_in[1]: (1024, 256) f32    weights uniform [0,1)
//   d_out:   (1024, 30522) f32  -- value = bf16(RN-even) of scatter-max of the
//            per-token weight into its vocab slot, 0 baseline, stored as f32.
//
// Session model (r0-r3): every timed iteration contains a ~75 us harness
// re-poison fill (488,352 KB = full 500 MB allocation) that we cannot
// remove. Controllable part = our kernel. Best so far: r1 fused (~55 us).
// r2 showed NT stores REGRESS (~+10 us: they force synchronous HBM
// write-through; regular stores retire into L2/L3 and drain lazily).
// r3 showed memset+global-atomics is no better (~60 us).
//
// r4: fused kernel, tuned. 8 vocab chunks/row -> 15.3 KB LDS -> 8 blocks/CU
// (full 32-wave occupancy, was 2 blocks/CU in r1). uint4 LDS zeroing
// (4 iters, was 60 scalar). Token load issued BEFORE the zero loop so HBM
// latency hides under ds_writes. Regular uint2 stores (8 B/lane sweet spot;
// row stride 122,088 B is only 8B-aligned, so uint4 would fault on odd rows).
// No memset, no global atomics; each output byte written exactly once.
#define VOCAB 30522
#define SEQ   256
#define NCH   8
#define CH    3816   // chunks 0..6 = 3816 slots, chunk 7 = 3810 (both even)

extern "C" __global__ __launch_bounds__(256)
void TargetEncoder_532575944857_kernel(const int* __restrict__ ids,
                                       const float* __restrict__ ws,
                                       unsigned int* __restrict__ out,
                                       int n_rows) {
    __shared__ __align__(16) unsigned int tab[CH];  // 15,264 B -> 8 blocks/CU

    const int blk  = blockIdx.x;
    const int b    = blk >> 3;            // row
    const int c    = blk & 7;             // vocab chunk
    const int t    = threadIdx.x;
    const int base = c * CH;
    const int lim  = (c == NCH - 1) ? (VOCAB - (NCH - 1) * CH) : CH;  // 3810 : 3816

    // Issue this block's token load FIRST; latency hides under LDS zeroing.
    const int   tok = b * SEQ + t;
    const int   id  = ids[tok];
    const float w   = ws[tok];

    // Phase 1: zero the LDS table with ds_write_b128 (this IS the 0 baseline).
    {
        const uint4 z = make_uint4(0u, 0u, 0u, 0u);
        uint4* t4 = (uint4*)tab;
        #pragma unroll
        for (int i = t; i < CH / 4; i += 256) t4[i] = z;   // 954 -> 4 iters
    }
    __syncthreads();

    // Phase 2: scatter-max this row's 256 tokens into LDS. bf16 RN-even of a
    // nonneg f32, re-expanded to f32 bits: nonneg IEEE bit patterns are
    // order-isomorphic to values and RN-even is monotone on nonneg inputs,
    // so round-then-max == max-then-round (bit-exact vs reference).
    // Duplicates resolved by the LDS atomic; ids outside this chunk (and any
    // defensive out-of-range id) fail the unsigned bound check.
    {
        const unsigned u   = __float_as_uint(w);
        const unsigned val = ((u + 0x7FFFu + ((u >> 16) & 1u)) >> 16) << 16;
        const int      loc = id - base;
        if (val != 0u && (unsigned)loc < (unsigned)lim)
            atomicMax(&tab[loc], val);
    }
    __syncthreads();

    // Phase 3: stream the chunk to global, coalesced regular uint2 stores
    // (8 B/lane, 512 B/wave; L2/L3 can absorb and drain lazily). lim is even
    // for all chunks -> uint2 loop covers everything, no scalar tail.
    unsigned long long*       dst = (unsigned long long*)(out + (long long)b * VOCAB + base);
    const unsigned long long* src = (const unsigned long long*)tab;
    const int n2 = lim >> 1;              // 1908 : 1905
    for (int j = t; j < n2; j += 256) dst[j] = src[j];
}

extern "C" void kernel_launch(void* const* d_in, const int* in_sizes, int n_in,
                              void* d_out, int out_size, void* d_ws, size_t ws_size,
                              hipStream_t stream) {
    const int*   ids = (const int*)d_in[0];
    const float* ws  = (const float*)d_in[1];
    const int n_tok  = in_sizes[0];        // 262144
    const int n_rows = n_tok / SEQ;        // 1024

    TargetEncoder_532575944857_kernel<<<dim3(n_rows * NCH), dim3(256), 0, stream>>>(
        ids, ws, (unsigned int*)d_out, n_rows);
}

// Round 5
// 128.471 us; speedup vs baseline: 1.0876x; 1.0145x over previous
//
#include <hip/hip_runtime.h>

// Problem shape (fixed):
//   d_in[0]: (1024, 256) int32  ids in [0, 30522)
//   d_in[1]: (1024, 256) f32    weights uniform [0,1)
//   d_out:   (1024, 30522) f32  -- value = bf16(RN-even) of scatter-max of the
//            per-token weight into its vocab slot, 0 baseline, stored as f32.
//
// Session model (r0-r4): every timed iteration contains a ~75 us harness
// re-poison fill (488,352 KB = full 500 MB allocation), unremovable.
// r4 post-mortem: occupancy/LDS-zero tuning moved only -1.5 us => the fused
// kernel's cost is the STORE LOOP (ds_read_b64 + lgkmcnt + store_b64 per
// 8 B), not the phases. The rocclr fill hits 6.6 TB/s with pure register
// stores at 9% occupancy -- that's the pattern to copy.
//
// r5: tab[] is ~99% zeros (<=256 tokens over 3816 slots). So: stream ZEROS
// from registers (dwordx4, no LDS in the stream, fill-kernel pattern),
// then write only the winning scattered values (<=256 dword stores/block).
// LDS remains only as the tiny max-resolution table. __syncthreads() drains
// vmcnt(0) before s_barrier, so zero stores are L2-acked before value
// stores issue (same CU => same XCD L2 => ordered). Duplicate-id winners
// store identical bits (benign). Bulk zero-store issues FIRST so all LDS
// work hides under outstanding global stores.
#define VOCAB 30522
#define SEQ   256
#define NCH   8
#define CH    3816   // chunks 0..6 = 3816 slots, chunk 7 = 3810

extern "C" __global__ __launch_bounds__(256)
void TargetEncoder_532575944857_kernel(const int* __restrict__ ids,
                                       const float* __restrict__ ws,
                                       unsigned int* __restrict__ out,
                                       int n_rows) {
    __shared__ __align__(16) unsigned int tab[CH];  // 15,264 B -> 8 blocks/CU

    const int blk  = blockIdx.x;
    const int b    = blk >> 3;            // row
    const int c    = blk & 7;             // vocab chunk
    const int t    = threadIdx.x;
    const int base = c * CH;
    const int lim  = (c == NCH - 1) ? (VOCAB - (NCH - 1) * CH) : CH;  // 3810 : 3816

    // Issue this block's token load first; latency hides under the zero-store.
    const int   tok = b * SEQ + t;
    const int   id  = ids[tok];
    const float w   = ws[tok];

    // Phase A: bulk zero-store of this chunk's global region. Pure register
    // stores (fill-kernel pattern), no LDS dependency, issued before any
    // barrier so everything else overlaps with them. Chunk byte base =
    // b*122088 + c*15264 is 8-mod-16 on odd rows -> generic 8 B head/tail
    // around an aligned uint4 body.
    {
        unsigned int* gp = out + (long long)b * VOCAB + base;
        uintptr_t p0   = (uintptr_t)gp;
        uintptr_t pend = p0 + ((uintptr_t)lim << 2);
        uintptr_t pa   = (p0 + 15) & ~(uintptr_t)15;
        uintptr_t pe   = pend & ~(uintptr_t)15;
        if (t == 0 && pa != p0)   *(uint2*)p0 = make_uint2(0u, 0u);  // 8 B head
        if (t == 1 && pe != pend) *(uint2*)pe = make_uint2(0u, 0u);  // 8 B tail
        uint4* d4 = (uint4*)pa;
        const int n4 = (int)((pe - pa) >> 4);               // 952..954
        const uint4 z4 = make_uint4(0u, 0u, 0u, 0u);
        for (int j = t; j < n4; j += 256) d4[j] = z4;       // ~4 iters/thread
    }

    // Phase B: zero the LDS max-table (overlaps with outstanding stores).
    {
        const uint4 z = make_uint4(0u, 0u, 0u, 0u);
        uint4* t4 = (uint4*)tab;
        for (int i = t; i < CH / 4; i += 256) t4[i] = z;    // 954 -> 4 iters
    }
    __syncthreads();

    // Phase C: LDS scatter-max. bf16 RN-even of a nonneg f32 re-expanded to
    // f32 bits: nonneg IEEE bit patterns are order-isomorphic to values and
    // RN-even is monotone on nonneg inputs, so round-then-max ==
    // max-then-round (bit-exact vs reference). Duplicates resolved by the
    // LDS atomic; out-of-chunk / defensive out-of-range ids fail the
    // unsigned bound check.
    const unsigned u   = __float_as_uint(w);
    const unsigned val = ((u + 0x7FFFu + ((u >> 16) & 1u)) >> 16) << 16;
    int loc = id - base;
    if (val != 0u && (unsigned)loc < (unsigned)lim)
        atomicMax(&tab[loc], val);
    else
        loc = -1;

    // Drains lgkmcnt (atomics done) AND vmcnt(0) (zero stores L2-acked),
    // so the value stores below are ordered after the zero stores.
    __syncthreads();

    // Phase D: winners write their value -- <=256 scattered 4 B stores/block
    // (~32 actual after duplicate collapse). Equal-bits duplicate winners
    // both store the same value: benign.
    if (loc >= 0 && tab[loc] == val)
        out[(long long)b * VOCAB + base + loc] = val;
}

extern "C" void kernel_launch(void* const* d_in, const int* in_sizes, int n_in,
                              void* d_out, int out_size, void* d_ws, size_t ws_size,
                              hipStream_t stream) {
    const int*   ids = (const int*)d_in[0];
    const float* ws  = (const float*)d_in[1];
    const int n_tok  = in_sizes[0];        // 262144
    const int n_rows = n_tok / SEQ;        // 1024

    TargetEncoder_532575944857_kernel<<<dim3(n_rows * NCH), dim3(256), 0, stream>>>(
        ids, ws, (unsigned int*)d_out, n_rows);
}